// Round 6
// baseline (308.759 us; speedup 1.0000x reference)
//
#include <hip/hip_runtime.h>
#include <hip/hip_bf16.h>

typedef __hip_bfloat16 bf16_t;
typedef __attribute__((ext_vector_type(8))) __bf16 bf16x8;
typedef __attribute__((ext_vector_type(4))) float f32x4;
typedef __attribute__((ext_vector_type(4))) unsigned short ushort4v;

#define NUM_B 2
#define NUM_H 16
#define SEQ   2048
#define EMB   1024
#define LOG2E 1.44269504088896340736f

// ---------------- cast fp32 -> bf16, 4 elems/thread ----------------
__global__ void cast_f32_bf16_kernel(const float* __restrict__ src,
                                     bf16_t* __restrict__ dst) {
  int i = (blockIdx.x * 256 + threadIdx.x) * 4;
  f32x4 v = *(const f32x4*)&src[i];
  ushort4v p;
#pragma unroll
  for (int j = 0; j < 4; ++j)
    p[j] = __builtin_bit_cast(unsigned short, __float2bfloat16(v[j]));
  *(ushort4v*)&dst[i] = p;
}

// ---------------- cast+transpose: dst[C x R] (bf16) = src[R x C]^T (fp32) ----------------
__global__ void transpose_cast_kernel(const float* __restrict__ src,
                                      bf16_t* __restrict__ dst, int R, int C) {
  __shared__ float tile[32][33];
  int c0 = blockIdx.x * 32, r0 = blockIdx.y * 32;
  int tx = threadIdx.x & 31, ty = threadIdx.x >> 5;
#pragma unroll
  for (int i = 0; i < 4; ++i)
    tile[ty + i * 8][tx] = src[(size_t)(r0 + ty + i * 8) * C + c0 + tx];
  __syncthreads();
#pragma unroll
  for (int i = 0; i < 4; ++i)
    dst[(size_t)(c0 + ty + i * 8) * R + r0 + tx] = __float2bfloat16(tile[tx][ty + i * 8]);
}

// ---------------- GEMM: C = A[M,K]bf16 * Bt[N,K]bf16^T + bias(f32) ----------------
__device__ __forceinline__ void stage_tile(const bf16_t* __restrict__ G,
                                           int row0, int col0, int ld,
                                           bf16_t* Ls, int wave, int lane) {
  // 128x32 bf16 tile = 8192B = 512 chunks of 16B; LDS dest = wave-uniform
  // base + lane*16 -- conforms to global_load_lds HW rule.
  int c0 = wave * 64 + lane;
  const char* g0 = (const char*)(G + (size_t)(row0 + (c0 >> 2)) * ld + col0) + (c0 & 3) * 16;
  char* l0 = (char*)Ls + c0 * 16;
  __builtin_amdgcn_global_load_lds((const __attribute__((address_space(1))) void*)g0,
                                   (__attribute__((address_space(3))) void*)l0, 16, 0, 0);
  int c1 = c0 + 256;
  const char* g1 = (const char*)(G + (size_t)(row0 + (c1 >> 2)) * ld + col0) + (c1 & 3) * 16;
  char* l1 = (char*)Ls + c1 * 16;
  __builtin_amdgcn_global_load_lds((const __attribute__((address_space(1))) void*)g1,
                                   (__attribute__((address_space(3))) void*)l1, 16, 0, 0);
}

// MODE 0: epilogue scatters bf16 into Q [BH,S,D], K [BH,S,D], Vt [BH,D,S]  (N=3072)
// MODE 1: plain fp32 store outf[m*Ndim + n]
template <int MODE>
__global__ __launch_bounds__(256) void gemm_bf16_kernel(
    const bf16_t* __restrict__ A, const bf16_t* __restrict__ Bt,
    const float* __restrict__ bias, bf16_t* __restrict__ out0,
    bf16_t* __restrict__ out1, bf16_t* __restrict__ out2,
    float* __restrict__ outf, int Ndim, int Kdim) {
  __shared__ __align__(16) bf16_t As[128 * 32];
  __shared__ __align__(16) bf16_t Bs[128 * 32];
  int tid = threadIdx.x;
  int wave = tid >> 6, lane = tid & 63;
  int lr = lane & 15, lq = lane >> 4;
  int m0 = blockIdx.x * 128, n0 = blockIdx.y * 128;
  int wm = (wave >> 1) * 64, wn = (wave & 1) * 64;
  f32x4 acc[4][4];
#pragma unroll
  for (int i = 0; i < 4; ++i)
#pragma unroll
    for (int j = 0; j < 4; ++j) acc[i][j] = (f32x4){0.f, 0.f, 0.f, 0.f};

  for (int k0 = 0; k0 < Kdim; k0 += 32) {
    __syncthreads();
    stage_tile(A, m0, k0, Kdim, As, wave, lane);
    stage_tile(Bt, n0, k0, Kdim, Bs, wave, lane);
    __syncthreads();
    bf16x8 af[4], bfr[4];
#pragma unroll
    for (int mt = 0; mt < 4; ++mt)
      af[mt] = *(const bf16x8*)&As[(wm + mt * 16 + lr) * 32 + lq * 8];
#pragma unroll
    for (int nt = 0; nt < 4; ++nt)
      bfr[nt] = *(const bf16x8*)&Bs[(wn + nt * 16 + lr) * 32 + lq * 8];
#pragma unroll
    for (int mt = 0; mt < 4; ++mt)
#pragma unroll
      for (int nt = 0; nt < 4; ++nt)
        acc[mt][nt] = __builtin_amdgcn_mfma_f32_16x16x32_bf16(af[mt], bfr[nt], acc[mt][nt], 0, 0, 0);
  }

#pragma unroll
  for (int nt = 0; nt < 4; ++nt) {
    int n = n0 + wn + nt * 16 + lr;
    float bv = bias[n];
    if (MODE == 0) {
      int sec = n >> 10;          // 0=q 1=k 2=v
      int h = (n >> 6) & (NUM_H - 1);
      int d = n & 63;
#pragma unroll
      for (int mt = 0; mt < 4; ++mt) {
        int mbase = m0 + wm + mt * 16 + lq * 4;   // 4 consecutive rows
        int b = mbase >> 11;
        int s = mbase & (SEQ - 1);
        int bh = b * NUM_H + h;
        if (sec == 2) {
          ushort4v pk;
#pragma unroll
          for (int r = 0; r < 4; ++r)
            pk[r] = __builtin_bit_cast(unsigned short, __float2bfloat16(acc[mt][nt][r] + bv));
          *(ushort4v*)&out2[((size_t)bh * 64 + d) * SEQ + s] = pk;
        } else {
          bf16_t* dst = (sec == 0) ? out0 : out1;
#pragma unroll
          for (int r = 0; r < 4; ++r)
            dst[((size_t)bh * SEQ + (s + r)) * 64 + d] = __float2bfloat16(acc[mt][nt][r] + bv);
        }
      }
    } else {
#pragma unroll
      for (int mt = 0; mt < 4; ++mt)
#pragma unroll
        for (int r = 0; r < 4; ++r) {
          int m = m0 + wm + mt * 16 + lq * 4 + r;
          outf[(size_t)m * Ndim + n] = acc[mt][nt][r] + bv;
        }
    }
  }
}

// ---------------- RoPE (GPT-NeoX rotate-half), Q gets 1/sqrt(D)=1/8 ----------------
__global__ void rope_kernel(bf16_t* __restrict__ Q, bf16_t* __restrict__ K) {
  int idx = blockIdx.x * blockDim.x + threadIdx.x;  // over B*H*S*32
  int i = idx & 31;
  int bhs = idx >> 5;
  int s = bhs & (SEQ - 1);
  float inv = exp2f(-(float)i * (13.287712379549449f / 32.0f));  // 10000^(-i/32)
  float f = (float)s * inv;
  float sn, cs;
  sincosf(f, &sn, &cs);
  size_t base = (size_t)bhs * 64;
  float q1 = __bfloat162float(Q[base + i]);
  float q2 = __bfloat162float(Q[base + i + 32]);
  float k1 = __bfloat162float(K[base + i]);
  float k2 = __bfloat162float(K[base + i + 32]);
  Q[base + i]      = __float2bfloat16((q1 * cs - q2 * sn) * 0.125f);
  Q[base + i + 32] = __float2bfloat16((q2 * cs + q1 * sn) * 0.125f);
  K[base + i]      = __float2bfloat16(k1 * cs - k2 * sn);
  K[base + i + 32] = __float2bfloat16(k2 * cs + k1 * sn);
}

// ---------------- flash attention v2: 256-thread blocks, q-tile 64, kv-chunk 64 ----------------
// Wave w owns q rows [q0+16w, q0+16w+15]. P round-trip uses a PRIVATE per-wave
// LDS slice -> no __syncthreads anywhere (same-wave DS ordering suffices).
// Psh stride 68: write banks = 8*lq + lr/2 + const -> conflict-free.
__global__ __launch_bounds__(256) void flash_attn_kernel(
    const bf16_t* __restrict__ Q, const bf16_t* __restrict__ K,
    const bf16_t* __restrict__ Vt, bf16_t* __restrict__ O) {
  __shared__ __align__(16) bf16_t Psh[4][16 * 68];
  int tid = threadIdx.x;
  int wv = tid >> 6, lane = tid & 63;
  int lr = lane & 15, lq = lane >> 4;
  int tile = blockIdx.x >> 5;     // 0..31
  int bh = blockIdx.x & 31;
  int q0 = tile * 64;
  int qw0 = q0 + wv * 16;
  const bf16_t* Qb = Q + (size_t)bh * SEQ * 64;
  const bf16_t* Kb = K + (size_t)bh * SEQ * 64;
  const bf16_t* Vb = Vt + (size_t)bh * 64 * SEQ;
  bf16_t* Pw = Psh[wv];

  bf16x8 aq0 = *(const bf16x8*)&Qb[(size_t)(qw0 + lr) * 64 + lq * 8];
  bf16x8 aq1 = *(const bf16x8*)&Qb[(size_t)(qw0 + lr) * 64 + 32 + lq * 8];

  f32x4 Oacc[4];
#pragma unroll
  for (int dt = 0; dt < 4; ++dt) Oacc[dt] = (f32x4){0.f, 0.f, 0.f, 0.f};
  float mrow[4] = {-1e30f, -1e30f, -1e30f, -1e30f};
  float lrow[4] = {0.f, 0.f, 0.f, 0.f};

  for (int ch = 0; ch <= tile; ++ch) {
    int kv0 = ch * 64;
    bool diag = (ch == tile);
    f32x4 sv[4];
#pragma unroll
    for (int sub = 0; sub < 4; ++sub) {
      bool active = !diag || (sub <= wv);      // wave-uniform
      if (active) {
        const bf16_t* kr = &Kb[(size_t)(kv0 + sub * 16 + lr) * 64 + lq * 8];
        bf16x8 k0 = *(const bf16x8*)kr;
        bf16x8 k1 = *(const bf16x8*)(kr + 32);
        f32x4 t = (f32x4){0.f, 0.f, 0.f, 0.f};
        t = __builtin_amdgcn_mfma_f32_16x16x32_bf16(aq0, k0, t, 0, 0, 0);
        t = __builtin_amdgcn_mfma_f32_16x16x32_bf16(aq1, k1, t, 0, 0, 0);
        if (diag && sub == wv) {               // only this sub needs element mask
#pragma unroll
          for (int r = 0; r < 4; ++r)
            if (lr > lq * 4 + r) t[r] = -1e30f;
        }
        sv[sub] = t;
      } else {
        sv[sub] = (f32x4){-1e30f, -1e30f, -1e30f, -1e30f};
      }
    }

    float al[4];
#pragma unroll
    for (int r = 0; r < 4; ++r) {
      float mx = fmaxf(fmaxf(sv[0][r], sv[1][r]), fmaxf(sv[2][r], sv[3][r]));
      mx = fmaxf(mx, __shfl_xor(mx, 1, 64));
      mx = fmaxf(mx, __shfl_xor(mx, 2, 64));
      mx = fmaxf(mx, __shfl_xor(mx, 4, 64));
      mx = fmaxf(mx, __shfl_xor(mx, 8, 64));
      float mn = fmaxf(mrow[r], mx);
      float p0 = exp2f((sv[0][r] - mn) * LOG2E);
      float p1 = exp2f((sv[1][r] - mn) * LOG2E);
      float p2 = exp2f((sv[2][r] - mn) * LOG2E);
      float p3 = exp2f((sv[3][r] - mn) * LOG2E);
      float ps = (p0 + p1) + (p2 + p3);
      ps += __shfl_xor(ps, 1, 64);
      ps += __shfl_xor(ps, 2, 64);
      ps += __shfl_xor(ps, 4, 64);
      ps += __shfl_xor(ps, 8, 64);
      al[r] = exp2f((mrow[r] - mn) * LOG2E);
      lrow[r] = lrow[r] * al[r] + ps;
      mrow[r] = mn;
      int row = lq * 4 + r;
      Pw[row * 68 + lr]      = __float2bfloat16(p0);
      Pw[row * 68 + 16 + lr] = __float2bfloat16(p1);
      Pw[row * 68 + 32 + lr] = __float2bfloat16(p2);
      Pw[row * 68 + 48 + lr] = __float2bfloat16(p3);
    }

    bf16x8 ap0 = *(const bf16x8*)&Pw[lr * 68 + lq * 8];
    bf16x8 ap1 = *(const bf16x8*)&Pw[lr * 68 + 32 + lq * 8];
#pragma unroll
    for (int dt = 0; dt < 4; ++dt) {
      const bf16_t* vr = &Vb[(size_t)(dt * 16 + lr) * SEQ + kv0 + lq * 8];
      bf16x8 v0 = *(const bf16x8*)vr;
      bf16x8 v1 = *(const bf16x8*)(vr + 32);
#pragma unroll
      for (int r = 0; r < 4; ++r) Oacc[dt][r] *= al[r];
      Oacc[dt] = __builtin_amdgcn_mfma_f32_16x16x32_bf16(ap0, v0, Oacc[dt], 0, 0, 0);
      Oacc[dt] = __builtin_amdgcn_mfma_f32_16x16x32_bf16(ap1, v1, Oacc[dt], 0, 0, 0);
    }
  }

  int b = bh >> 4, h = bh & (NUM_H - 1);
#pragma unroll
  for (int dt = 0; dt < 4; ++dt)
#pragma unroll
    for (int r = 0; r < 4; ++r) {
      int q = qw0 + lq * 4 + r;
      O[(((size_t)b * SEQ + q) * NUM_H + h) * 64 + dt * 16 + lr] =
          __float2bfloat16(Oacc[dt][r] / lrow[r]);
    }
}

extern "C" void kernel_launch(void* const* d_in, const int* in_sizes, int n_in,
                              void* d_out, int out_size, void* d_ws, size_t ws_size,
                              hipStream_t stream) {
  const float* x      = (const float*)d_in[0];
  const float* w_qkv  = (const float*)d_in[1];
  const float* b_qkv  = (const float*)d_in[2];
  const float* w_o    = (const float*)d_in[3];
  const float* b_o    = (const float*)d_in[4];
  float* out = (float*)d_out;

  bf16_t* ws    = (bf16_t*)d_ws;
  bf16_t* xb    = ws;                       // [4096,1024]   8MB
  bf16_t* wqkvT = xb + 4 * 1024 * 1024;     // [3072,1024]   6MB
  bf16_t* woT   = wqkvT + 3072 * 1024;      // [1024,1024]   2MB
  bf16_t* Qb    = woT + 1024 * 1024;        // [32,2048,64]  8MB
  bf16_t* Kb    = Qb + 4 * 1024 * 1024;     // [32,2048,64]  8MB
  bf16_t* Vt    = Kb + 4 * 1024 * 1024;     // [32,64,2048]  8MB
  bf16_t* attn  = Vt + 4 * 1024 * 1024;     // [4096,1024]   8MB  (48MB total)

  cast_f32_bf16_kernel<<<4096, 256, 0, stream>>>(x, xb);
  transpose_cast_kernel<<<dim3(96, 32), 256, 0, stream>>>(w_qkv, wqkvT, 1024, 3072);
  transpose_cast_kernel<<<dim3(32, 32), 256, 0, stream>>>(w_o, woT, 1024, 1024);
  gemm_bf16_kernel<0><<<dim3(32, 24), 256, 0, stream>>>(xb, wqkvT, b_qkv, Qb, Kb, Vt, nullptr, 3072, 1024);
  rope_kernel<<<8192, 256, 0, stream>>>(Qb, Kb);
  flash_attn_kernel<<<1024, 256, 0, stream>>>(Qb, Kb, Vt, attn);
  gemm_bf16_kernel<1><<<dim3(32, 8), 256, 0, stream>>>(attn, woT, b_o, nullptr, nullptr, nullptr, out, 1024, 1024);
}

// Round 7
// 298.533 us; speedup vs baseline: 1.0343x; 1.0343x over previous
//
#include <hip/hip_runtime.h>
#include <hip/hip_bf16.h>

typedef __hip_bfloat16 bf16_t;
typedef __attribute__((ext_vector_type(8))) __bf16 bf16x8;
typedef __attribute__((ext_vector_type(4))) float f32x4;
typedef __attribute__((ext_vector_type(4))) unsigned short ushort4v;

#define NUM_B 2
#define NUM_H 16
#define SEQ   2048
#define EMB   1024
#define LOG2E 1.44269504088896340736f

// ---------------- cast fp32 -> bf16, 4 elems/thread ----------------
__global__ void cast_f32_bf16_kernel(const float* __restrict__ src,
                                     bf16_t* __restrict__ dst) {
  int i = (blockIdx.x * 256 + threadIdx.x) * 4;
  f32x4 v = *(const f32x4*)&src[i];
  ushort4v p;
#pragma unroll
  for (int j = 0; j < 4; ++j)
    p[j] = __builtin_bit_cast(unsigned short, __float2bfloat16(v[j]));
  *(ushort4v*)&dst[i] = p;
}

// ---------------- cast+transpose: dst[C x R] (bf16) = src[R x C]^T (fp32) ----------------
__global__ void transpose_cast_kernel(const float* __restrict__ src,
                                      bf16_t* __restrict__ dst, int R, int C) {
  __shared__ float tile[32][33];
  int c0 = blockIdx.x * 32, r0 = blockIdx.y * 32;
  int tx = threadIdx.x & 31, ty = threadIdx.x >> 5;
#pragma unroll
  for (int i = 0; i < 4; ++i)
    tile[ty + i * 8][tx] = src[(size_t)(r0 + ty + i * 8) * C + c0 + tx];
  __syncthreads();
#pragma unroll
  for (int i = 0; i < 4; ++i)
    dst[(size_t)(c0 + ty + i * 8) * R + r0 + tx] = __float2bfloat16(tile[tx][ty + i * 8]);
}

// ---------------- GEMM: C = A[M,K]bf16 * Bt[N,K]bf16^T + bias(f32) ----------------
__device__ __forceinline__ void stage_tile(const bf16_t* __restrict__ G,
                                           int row0, int col0, int ld,
                                           bf16_t* Ls, int wave, int lane) {
  int c0 = wave * 64 + lane;
  const char* g0 = (const char*)(G + (size_t)(row0 + (c0 >> 2)) * ld + col0) + (c0 & 3) * 16;
  char* l0 = (char*)Ls + c0 * 16;
  __builtin_amdgcn_global_load_lds((const __attribute__((address_space(1))) void*)g0,
                                   (__attribute__((address_space(3))) void*)l0, 16, 0, 0);
  int c1 = c0 + 256;
  const char* g1 = (const char*)(G + (size_t)(row0 + (c1 >> 2)) * ld + col0) + (c1 & 3) * 16;
  char* l1 = (char*)Ls + c1 * 16;
  __builtin_amdgcn_global_load_lds((const __attribute__((address_space(1))) void*)g1,
                                   (__attribute__((address_space(3))) void*)l1, 16, 0, 0);
}

// MODE 0: epilogue scatters bf16 into Q [BH,S,D], K [BH,S,D], Vt [BH,D,S]  (N=3072)
// MODE 1: plain fp32 store outf[m*Ndim + n]
template <int MODE>
__global__ __launch_bounds__(256) void gemm_bf16_kernel(
    const bf16_t* __restrict__ A, const bf16_t* __restrict__ Bt,
    const float* __restrict__ bias, bf16_t* __restrict__ out0,
    bf16_t* __restrict__ out1, bf16_t* __restrict__ out2,
    float* __restrict__ outf, int Ndim, int Kdim) {
  __shared__ __align__(16) bf16_t As[128 * 32];
  __shared__ __align__(16) bf16_t Bs[128 * 32];
  int tid = threadIdx.x;
  int wave = tid >> 6, lane = tid & 63;
  int lr = lane & 15, lq = lane >> 4;
  int m0 = blockIdx.x * 128, n0 = blockIdx.y * 128;
  int wm = (wave >> 1) * 64, wn = (wave & 1) * 64;
  f32x4 acc[4][4];
#pragma unroll
  for (int i = 0; i < 4; ++i)
#pragma unroll
    for (int j = 0; j < 4; ++j) acc[i][j] = (f32x4){0.f, 0.f, 0.f, 0.f};

  for (int k0 = 0; k0 < Kdim; k0 += 32) {
    __syncthreads();
    stage_tile(A, m0, k0, Kdim, As, wave, lane);
    stage_tile(Bt, n0, k0, Kdim, Bs, wave, lane);
    __syncthreads();
    bf16x8 af[4], bfr[4];
#pragma unroll
    for (int mt = 0; mt < 4; ++mt)
      af[mt] = *(const bf16x8*)&As[(wm + mt * 16 + lr) * 32 + lq * 8];
#pragma unroll
    for (int nt = 0; nt < 4; ++nt)
      bfr[nt] = *(const bf16x8*)&Bs[(wn + nt * 16 + lr) * 32 + lq * 8];
#pragma unroll
    for (int mt = 0; mt < 4; ++mt)
#pragma unroll
      for (int nt = 0; nt < 4; ++nt)
        acc[mt][nt] = __builtin_amdgcn_mfma_f32_16x16x32_bf16(af[mt], bfr[nt], acc[mt][nt], 0, 0, 0);
  }

#pragma unroll
  for (int nt = 0; nt < 4; ++nt) {
    int n = n0 + wn + nt * 16 + lr;
    float bv = bias[n];
    if (MODE == 0) {
      int sec = n >> 10;          // 0=q 1=k 2=v
      int h = (n >> 6) & (NUM_H - 1);
      int d = n & 63;
#pragma unroll
      for (int mt = 0; mt < 4; ++mt) {
        int mbase = m0 + wm + mt * 16 + lq * 4;   // 4 consecutive rows
        int b = mbase >> 11;
        int s = mbase & (SEQ - 1);
        int bh = b * NUM_H + h;
        if (sec == 2) {
          ushort4v pk;
#pragma unroll
          for (int r = 0; r < 4; ++r)
            pk[r] = __builtin_bit_cast(unsigned short, __float2bfloat16(acc[mt][nt][r] + bv));
          *(ushort4v*)&out2[((size_t)bh * 64 + d) * SEQ + s] = pk;
        } else {
          bf16_t* dst = (sec == 0) ? out0 : out1;
#pragma unroll
          for (int r = 0; r < 4; ++r)
            dst[((size_t)bh * SEQ + (s + r)) * 64 + d] = __float2bfloat16(acc[mt][nt][r] + bv);
        }
      }
    } else {
#pragma unroll
      for (int mt = 0; mt < 4; ++mt)
#pragma unroll
        for (int r = 0; r < 4; ++r) {
          int m = m0 + wm + mt * 16 + lq * 4 + r;
          outf[(size_t)m * Ndim + n] = acc[mt][nt][r] + bv;
        }
    }
  }
}

// ---------------- RoPE (GPT-NeoX rotate-half), Q gets 1/sqrt(D)=1/8 ----------------
__global__ void rope_kernel(bf16_t* __restrict__ Q, bf16_t* __restrict__ K) {
  int idx = blockIdx.x * blockDim.x + threadIdx.x;  // over B*H*S*32
  int i = idx & 31;
  int bhs = idx >> 5;
  int s = bhs & (SEQ - 1);
  float inv = exp2f(-(float)i * (13.287712379549449f / 32.0f));  // 10000^(-i/32)
  float f = (float)s * inv;
  float sn, cs;
  sincosf(f, &sn, &cs);
  size_t base = (size_t)bhs * 64;
  float q1 = __bfloat162float(Q[base + i]);
  float q2 = __bfloat162float(Q[base + i + 32]);
  float k1 = __bfloat162float(K[base + i]);
  float k2 = __bfloat162float(K[base + i + 32]);
  Q[base + i]      = __float2bfloat16((q1 * cs - q2 * sn) * 0.125f);
  Q[base + i + 32] = __float2bfloat16((q2 * cs + q1 * sn) * 0.125f);
  K[base + i]      = __float2bfloat16(k1 * cs - k2 * sn);
  K[base + i + 32] = __float2bfloat16(k2 * cs + k1 * sn);
}

// ---------------- flash attention v3: S^T/O^T formulation ----------------
// S^T = K·Q^T  (A=K rows m=kv, B=Q rows n=q) -> C-layout lane holds ONE q (=lr),
// 16 kv values in-lane => row max/sum = in-lane tree + 2 shuffles (xor16/32).
// O^T = Vt·P  (A=Vt rows m=d, B=P n=q) -> O^T col is also q=lr: m/l/alpha all
// per-lane scalars, no cross-lane rescale. P via private per-wave LDS slice
// (barrier-free), packed b64 writes. Longest-tile-first block remap.
__global__ __launch_bounds__(256) void flash_attn_kernel(
    const bf16_t* __restrict__ Q, const bf16_t* __restrict__ K,
    const bf16_t* __restrict__ Vt, bf16_t* __restrict__ O) {
  __shared__ __align__(16) bf16_t Psh[4][16 * 68];
  int tid = threadIdx.x;
  int wv = tid >> 6, lane = tid & 63;
  int lr = lane & 15, lq = lane >> 4;
  int bx = blockIdx.x;
  int bh = bx & 31;
  int tile = 31 - (bx >> 5);      // longest blocks dispatched first
  int q0 = tile * 64;
  int qw0 = q0 + wv * 16;
  const bf16_t* Qb = Q + (size_t)bh * SEQ * 64;
  const bf16_t* Kb = K + (size_t)bh * SEQ * 64;
  const bf16_t* Vb = Vt + (size_t)bh * 64 * SEQ;
  bf16_t* Pw = Psh[wv];

  // Q as B-operand: lane supplies Q[qw0+lr][lq*8+j]
  bf16x8 aq0 = *(const bf16x8*)&Qb[(size_t)(qw0 + lr) * 64 + lq * 8];
  bf16x8 aq1 = *(const bf16x8*)&Qb[(size_t)(qw0 + lr) * 64 + 32 + lq * 8];

  f32x4 Oacc[4];
#pragma unroll
  for (int dt = 0; dt < 4; ++dt) Oacc[dt] = (f32x4){0.f, 0.f, 0.f, 0.f};
  float mrow = -1e30f, lrow = 0.f;   // per-lane scalars (q = lr)

  for (int ch = 0; ch <= tile; ++ch) {
    int kv0 = ch * 64;
    bool diag = (ch == tile);
    f32x4 sv[4];
#pragma unroll
    for (int sub = 0; sub < 4; ++sub) {
      if (!diag || sub <= wv) {    // wave-uniform
        const bf16_t* kr = &Kb[(size_t)(kv0 + sub * 16 + lr) * 64 + lq * 8];
        bf16x8 k0 = *(const bf16x8*)kr;
        bf16x8 k1 = *(const bf16x8*)(kr + 32);
        f32x4 t = (f32x4){0.f, 0.f, 0.f, 0.f};
        t = __builtin_amdgcn_mfma_f32_16x16x32_bf16(k0, aq0, t, 0, 0, 0);
        t = __builtin_amdgcn_mfma_f32_16x16x32_bf16(k1, aq1, t, 0, 0, 0);
        if (diag && sub == wv) {   // element mask: kv_local > q_local
#pragma unroll
          for (int r = 0; r < 4; ++r)
            if (lq * 4 + r > lr) t[r] = -1e30f;
        }
        sv[sub] = t;
      } else {
        sv[sub] = (f32x4){-1e30f, -1e30f, -1e30f, -1e30f};
      }
    }

    // row max: in-lane tree over 16 values + 2 shuffles across quads
    f32x4 m01 = (f32x4){fmaxf(sv[0][0], sv[1][0]), fmaxf(sv[0][1], sv[1][1]),
                        fmaxf(sv[0][2], sv[1][2]), fmaxf(sv[0][3], sv[1][3])};
    f32x4 m23 = (f32x4){fmaxf(sv[2][0], sv[3][0]), fmaxf(sv[2][1], sv[3][1]),
                        fmaxf(sv[2][2], sv[3][2]), fmaxf(sv[2][3], sv[3][3])};
    float mx = fmaxf(fmaxf(fmaxf(m01[0], m01[1]), fmaxf(m01[2], m01[3])),
                     fmaxf(fmaxf(m23[0], m23[1]), fmaxf(m23[2], m23[3])));
    mx = fmaxf(mx, __shfl_xor(mx, 16, 64));
    mx = fmaxf(mx, __shfl_xor(mx, 32, 64));
    float mn = fmaxf(mrow, mx);

    float p[4][4];
    float ps = 0.f;
#pragma unroll
    for (int sub = 0; sub < 4; ++sub) {
      ushort4v pk;
#pragma unroll
      for (int r = 0; r < 4; ++r) {
        p[sub][r] = exp2f((sv[sub][r] - mn) * LOG2E);
        pk[r] = __builtin_bit_cast(unsigned short, __float2bfloat16(p[sub][r]));
      }
      // P[q=lr][kv=sub*16+lq*4 .. +3] packed 8B write
      *(ushort4v*)&Pw[lr * 68 + sub * 16 + lq * 4] = pk;
      ps += (p[sub][0] + p[sub][1]) + (p[sub][2] + p[sub][3]);
    }
    ps += __shfl_xor(ps, 16, 64);
    ps += __shfl_xor(ps, 32, 64);

    float al = exp2f((mrow - mn) * LOG2E);
    lrow = lrow * al + ps;
    mrow = mn;

    // B-fragment of P: lane supplies P[kv=lq*8+j][q... read Pw[q=lr][kv contiguous]
    bf16x8 ap0 = *(const bf16x8*)&Pw[lr * 68 + lq * 8];
    bf16x8 ap1 = *(const bf16x8*)&Pw[lr * 68 + 32 + lq * 8];
#pragma unroll
    for (int dt = 0; dt < 4; ++dt) {
      const bf16_t* vr = &Vb[(size_t)(dt * 16 + lr) * SEQ + kv0 + lq * 8];
      bf16x8 v0 = *(const bf16x8*)vr;
      bf16x8 v1 = *(const bf16x8*)(vr + 32);
#pragma unroll
      for (int r = 0; r < 4; ++r) Oacc[dt][r] *= al;
      Oacc[dt] = __builtin_amdgcn_mfma_f32_16x16x32_bf16(v0, ap0, Oacc[dt], 0, 0, 0);
      Oacc[dt] = __builtin_amdgcn_mfma_f32_16x16x32_bf16(v1, ap1, Oacc[dt], 0, 0, 0);
    }
  }

  // O^T[d=dt*16+lq*4+r][q=lr]; store packed 4 consecutive d per dt
  int b = bh >> 4, h = bh & (NUM_H - 1);
  int q = qw0 + lr;
  size_t base = (((size_t)b * SEQ + q) * NUM_H + h) * 64;
  float rinv = 1.0f / lrow;
#pragma unroll
  for (int dt = 0; dt < 4; ++dt) {
    ushort4v ok;
#pragma unroll
    for (int r = 0; r < 4; ++r)
      ok[r] = __builtin_bit_cast(unsigned short, __float2bfloat16(Oacc[dt][r] * rinv));
    *(ushort4v*)&O[base + dt * 16 + lq * 4] = ok;
  }
}

extern "C" void kernel_launch(void* const* d_in, const int* in_sizes, int n_in,
                              void* d_out, int out_size, void* d_ws, size_t ws_size,
                              hipStream_t stream) {
  const float* x      = (const float*)d_in[0];
  const float* w_qkv  = (const float*)d_in[1];
  const float* b_qkv  = (const float*)d_in[2];
  const float* w_o    = (const float*)d_in[3];
  const float* b_o    = (const float*)d_in[4];
  float* out = (float*)d_out;

  bf16_t* ws    = (bf16_t*)d_ws;
  bf16_t* xb    = ws;                       // [4096,1024]   8MB
  bf16_t* wqkvT = xb + 4 * 1024 * 1024;     // [3072,1024]   6MB
  bf16_t* woT   = wqkvT + 3072 * 1024;      // [1024,1024]   2MB
  bf16_t* Qb    = woT + 1024 * 1024;        // [32,2048,64]  8MB
  bf16_t* Kb    = Qb + 4 * 1024 * 1024;     // [32,2048,64]  8MB
  bf16_t* Vt    = Kb + 4 * 1024 * 1024;     // [32,64,2048]  8MB
  bf16_t* attn  = Vt + 4 * 1024 * 1024;     // [4096,1024]   8MB  (48MB total)

  cast_f32_bf16_kernel<<<4096, 256, 0, stream>>>(x, xb);
  transpose_cast_kernel<<<dim3(96, 32), 256, 0, stream>>>(w_qkv, wqkvT, 1024, 3072);
  transpose_cast_kernel<<<dim3(32, 32), 256, 0, stream>>>(w_o, woT, 1024, 1024);
  gemm_bf16_kernel<0><<<dim3(32, 24), 256, 0, stream>>>(xb, wqkvT, b_qkv, Qb, Kb, Vt, nullptr, 3072, 1024);
  rope_kernel<<<8192, 256, 0, stream>>>(Qb, Kb);
  flash_attn_kernel<<<1024, 256, 0, stream>>>(Qb, Kb, Vt, attn);
  gemm_bf16_kernel<1><<<dim3(32, 8), 256, 0, stream>>>(attn, woT, b_o, nullptr, nullptr, nullptr, out, 1024, 1024);
}

// Round 8
// 287.730 us; speedup vs baseline: 1.0731x; 1.0375x over previous
//
#include <hip/hip_runtime.h>
#include <hip/hip_bf16.h>

typedef __hip_bfloat16 bf16_t;
typedef __attribute__((ext_vector_type(8))) __bf16 bf16x8;
typedef __attribute__((ext_vector_type(4))) float f32x4;
typedef __attribute__((ext_vector_type(4))) unsigned short ushort4v;

#define NUM_B 2
#define NUM_H 16
#define SEQ   2048
#define EMB   1024
#define LOG2E 1.44269504088896340736f

// ---------------- cast fp32 -> bf16, 4 elems/thread ----------------
__global__ void cast_f32_bf16_kernel(const float* __restrict__ src,
                                     bf16_t* __restrict__ dst) {
  int i = (blockIdx.x * 256 + threadIdx.x) * 4;
  f32x4 v = *(const f32x4*)&src[i];
  ushort4v p;
#pragma unroll
  for (int j = 0; j < 4; ++j)
    p[j] = __builtin_bit_cast(unsigned short, __float2bfloat16(v[j]));
  *(ushort4v*)&dst[i] = p;
}

// ---------------- cast+transpose: dst[C x R] (bf16) = src[R x C]^T (fp32) ----------------
__global__ void transpose_cast_kernel(const float* __restrict__ src,
                                      bf16_t* __restrict__ dst, int R, int C) {
  __shared__ float tile[32][33];
  int c0 = blockIdx.x * 32, r0 = blockIdx.y * 32;
  int tx = threadIdx.x & 31, ty = threadIdx.x >> 5;
#pragma unroll
  for (int i = 0; i < 4; ++i)
    tile[ty + i * 8][tx] = src[(size_t)(r0 + ty + i * 8) * C + c0 + tx];
  __syncthreads();
#pragma unroll
  for (int i = 0; i < 4; ++i)
    dst[(size_t)(c0 + ty + i * 8) * R + r0 + tx] = __float2bfloat16(tile[tx][ty + i * 8]);
}

// ---------------- GEMM: C = A[M,K]bf16 * Bt[N,K]bf16^T + bias(f32) ----------------
__device__ __forceinline__ void stage_tile(const bf16_t* __restrict__ G,
                                           int row0, int col0, int ld,
                                           bf16_t* Ls, int wave, int lane) {
  int c0 = wave * 64 + lane;
  const char* g0 = (const char*)(G + (size_t)(row0 + (c0 >> 2)) * ld + col0) + (c0 & 3) * 16;
  char* l0 = (char*)Ls + c0 * 16;
  __builtin_amdgcn_global_load_lds((const __attribute__((address_space(1))) void*)g0,
                                   (__attribute__((address_space(3))) void*)l0, 16, 0, 0);
  int c1 = c0 + 256;
  const char* g1 = (const char*)(G + (size_t)(row0 + (c1 >> 2)) * ld + col0) + (c1 & 3) * 16;
  char* l1 = (char*)Ls + c1 * 16;
  __builtin_amdgcn_global_load_lds((const __attribute__((address_space(1))) void*)g1,
                                   (__attribute__((address_space(3))) void*)l1, 16, 0, 0);
}

// MODE 0: epilogue scatters bf16 into Q [BH,S,D], K [BH,S,D], Vt [BH,D,S]  (N=3072)
// MODE 1: plain fp32 store outf[m*Ndim + n]
template <int MODE>
__global__ __launch_bounds__(256) void gemm_bf16_kernel(
    const bf16_t* __restrict__ A, const bf16_t* __restrict__ Bt,
    const float* __restrict__ bias, bf16_t* __restrict__ out0,
    bf16_t* __restrict__ out1, bf16_t* __restrict__ out2,
    float* __restrict__ outf, int Ndim, int Kdim) {
  __shared__ __align__(16) bf16_t As[128 * 32];
  __shared__ __align__(16) bf16_t Bs[128 * 32];
  int tid = threadIdx.x;
  int wave = tid >> 6, lane = tid & 63;
  int lr = lane & 15, lq = lane >> 4;
  int m0 = blockIdx.x * 128, n0 = blockIdx.y * 128;
  int wm = (wave >> 1) * 64, wn = (wave & 1) * 64;
  f32x4 acc[4][4];
#pragma unroll
  for (int i = 0; i < 4; ++i)
#pragma unroll
    for (int j = 0; j < 4; ++j) acc[i][j] = (f32x4){0.f, 0.f, 0.f, 0.f};

  for (int k0 = 0; k0 < Kdim; k0 += 32) {
    __syncthreads();
    stage_tile(A, m0, k0, Kdim, As, wave, lane);
    stage_tile(Bt, n0, k0, Kdim, Bs, wave, lane);
    __syncthreads();
    bf16x8 af[4], bfr[4];
#pragma unroll
    for (int mt = 0; mt < 4; ++mt)
      af[mt] = *(const bf16x8*)&As[(wm + mt * 16 + lr) * 32 + lq * 8];
#pragma unroll
    for (int nt = 0; nt < 4; ++nt)
      bfr[nt] = *(const bf16x8*)&Bs[(wn + nt * 16 + lr) * 32 + lq * 8];
#pragma unroll
    for (int mt = 0; mt < 4; ++mt)
#pragma unroll
      for (int nt = 0; nt < 4; ++nt)
        acc[mt][nt] = __builtin_amdgcn_mfma_f32_16x16x32_bf16(af[mt], bfr[nt], acc[mt][nt], 0, 0, 0);
  }

#pragma unroll
  for (int nt = 0; nt < 4; ++nt) {
    int n = n0 + wn + nt * 16 + lr;
    float bv = bias[n];
    if (MODE == 0) {
      int sec = n >> 10;          // 0=q 1=k 2=v
      int h = (n >> 6) & (NUM_H - 1);
      int d = n & 63;
#pragma unroll
      for (int mt = 0; mt < 4; ++mt) {
        int mbase = m0 + wm + mt * 16 + lq * 4;   // 4 consecutive rows
        int b = mbase >> 11;
        int s = mbase & (SEQ - 1);
        int bh = b * NUM_H + h;
        if (sec == 2) {
          ushort4v pk;
#pragma unroll
          for (int r = 0; r < 4; ++r)
            pk[r] = __builtin_bit_cast(unsigned short, __float2bfloat16(acc[mt][nt][r] + bv));
          *(ushort4v*)&out2[((size_t)bh * 64 + d) * SEQ + s] = pk;
        } else {
          bf16_t* dst = (sec == 0) ? out0 : out1;
#pragma unroll
          for (int r = 0; r < 4; ++r)
            dst[((size_t)bh * SEQ + (s + r)) * 64 + d] = __float2bfloat16(acc[mt][nt][r] + bv);
        }
      }
    } else {
#pragma unroll
      for (int mt = 0; mt < 4; ++mt)
#pragma unroll
        for (int r = 0; r < 4; ++r) {
          int m = m0 + wm + mt * 16 + lq * 4 + r;
          outf[(size_t)m * Ndim + n] = acc[mt][nt][r] + bv;
        }
    }
  }
}

// ---------------- RoPE (GPT-NeoX rotate-half), Q gets 1/sqrt(D)=1/8 ----------------
__global__ void rope_kernel(bf16_t* __restrict__ Q, bf16_t* __restrict__ K) {
  int idx = blockIdx.x * blockDim.x + threadIdx.x;  // over B*H*S*32
  int i = idx & 31;
  int bhs = idx >> 5;
  int s = bhs & (SEQ - 1);
  float inv = exp2f(-(float)i * (13.287712379549449f / 32.0f));  // 10000^(-i/32)
  float f = (float)s * inv;
  float sn, cs;
  sincosf(f, &sn, &cs);
  size_t base = (size_t)bhs * 64;
  float q1 = __bfloat162float(Q[base + i]);
  float q2 = __bfloat162float(Q[base + i + 32]);
  float k1 = __bfloat162float(K[base + i]);
  float k2 = __bfloat162float(K[base + i + 32]);
  Q[base + i]      = __float2bfloat16((q1 * cs - q2 * sn) * 0.125f);
  Q[base + i + 32] = __float2bfloat16((q2 * cs + q1 * sn) * 0.125f);
  K[base + i]      = __float2bfloat16(k1 * cs - k2 * sn);
  K[base + i + 32] = __float2bfloat16(k2 * cs + k1 * sn);
}

// ---------------- flash attention v4: S^T/O^T + K register double-buffer ----------------
// v3 structure (S^T = K·Q^T so softmax is 2 shuffles; O^T = Vt·P so rescale is
// per-lane) + software pipeline: K of chunk ch+1 is loaded into registers while
// chunk ch computes; V loads hoisted to chunk start so softmax covers their
// latency. No barriers (private per-wave P slice in LDS).
__global__ __launch_bounds__(256) void flash_attn_kernel(
    const bf16_t* __restrict__ Q, const bf16_t* __restrict__ K,
    const bf16_t* __restrict__ Vt, bf16_t* __restrict__ O) {
  __shared__ __align__(16) bf16_t Psh[4][16 * 68];
  int tid = threadIdx.x;
  int wv = tid >> 6, lane = tid & 63;
  int lr = lane & 15, lq = lane >> 4;
  int bx = blockIdx.x;
  int bh = bx & 31;
  int tile = 31 - (bx >> 5);      // longest blocks dispatched first
  int q0 = tile * 64;
  int qw0 = q0 + wv * 16;
  const bf16_t* Qb = Q + (size_t)bh * SEQ * 64;
  const bf16_t* Kb = K + (size_t)bh * SEQ * 64;
  const bf16_t* Vb = Vt + (size_t)bh * 64 * SEQ;
  bf16_t* Pw = Psh[wv];

  // Q as B-operand: lane supplies Q[qw0+lr][lq*8+j]
  bf16x8 aq0 = *(const bf16x8*)&Qb[(size_t)(qw0 + lr) * 64 + lq * 8];
  bf16x8 aq1 = *(const bf16x8*)&Qb[(size_t)(qw0 + lr) * 64 + 32 + lq * 8];

  f32x4 Oacc[4];
#pragma unroll
  for (int dt = 0; dt < 4; ++dt) Oacc[dt] = (f32x4){0.f, 0.f, 0.f, 0.f};
  float mrow = -1e30f, lrow = 0.f;   // per-lane scalars (q = lr)

  // K double-buffer: preload chunk 0
  bf16x8 kc[4][2], kn[4][2];
#pragma unroll
  for (int sub = 0; sub < 4; ++sub) {
    const bf16_t* kr = &Kb[(size_t)(sub * 16 + lr) * 64 + lq * 8];
    kc[sub][0] = *(const bf16x8*)kr;
    kc[sub][1] = *(const bf16x8*)(kr + 32);
  }

  for (int ch = 0; ch <= tile; ++ch) {
    int kv0 = ch * 64;
    bool diag = (ch == tile);

    // V loads issued early: ~500 cyc of softmax/LDS work before first use
    bf16x8 vv[4][2];
#pragma unroll
    for (int dt = 0; dt < 4; ++dt) {
      const bf16_t* vr = &Vb[(size_t)(dt * 16 + lr) * SEQ + kv0 + lq * 8];
      vv[dt][0] = *(const bf16x8*)vr;
      vv[dt][1] = *(const bf16x8*)(vr + 32);
    }
    // prefetch next chunk's K: a full chunk of compute before first use
    if (ch < tile) {
      int kvn = kv0 + 64;
#pragma unroll
      for (int sub = 0; sub < 4; ++sub) {
        const bf16_t* kr = &Kb[(size_t)(kvn + sub * 16 + lr) * 64 + lq * 8];
        kn[sub][0] = *(const bf16x8*)kr;
        kn[sub][1] = *(const bf16x8*)(kr + 32);
      }
    }

    f32x4 sv[4];
#pragma unroll
    for (int sub = 0; sub < 4; ++sub) {
      if (!diag || sub <= wv) {    // wave-uniform
        f32x4 t = (f32x4){0.f, 0.f, 0.f, 0.f};
        t = __builtin_amdgcn_mfma_f32_16x16x32_bf16(kc[sub][0], aq0, t, 0, 0, 0);
        t = __builtin_amdgcn_mfma_f32_16x16x32_bf16(kc[sub][1], aq1, t, 0, 0, 0);
        if (diag && sub == wv) {   // element mask: kv_local > q_local
#pragma unroll
          for (int r = 0; r < 4; ++r)
            if (lq * 4 + r > lr) t[r] = -1e30f;
        }
        sv[sub] = t;
      } else {
        sv[sub] = (f32x4){-1e30f, -1e30f, -1e30f, -1e30f};
      }
    }

    // row max: in-lane tree over 16 values + 2 shuffles across quads
    f32x4 m01 = (f32x4){fmaxf(sv[0][0], sv[1][0]), fmaxf(sv[0][1], sv[1][1]),
                        fmaxf(sv[0][2], sv[1][2]), fmaxf(sv[0][3], sv[1][3])};
    f32x4 m23 = (f32x4){fmaxf(sv[2][0], sv[3][0]), fmaxf(sv[2][1], sv[3][1]),
                        fmaxf(sv[2][2], sv[3][2]), fmaxf(sv[2][3], sv[3][3])};
    float mx = fmaxf(fmaxf(fmaxf(m01[0], m01[1]), fmaxf(m01[2], m01[3])),
                     fmaxf(fmaxf(m23[0], m23[1]), fmaxf(m23[2], m23[3])));
    mx = fmaxf(mx, __shfl_xor(mx, 16, 64));
    mx = fmaxf(mx, __shfl_xor(mx, 32, 64));
    float mn = fmaxf(mrow, mx);

    float p[4][4];
    float ps = 0.f;
#pragma unroll
    for (int sub = 0; sub < 4; ++sub) {
      ushort4v pk;
#pragma unroll
      for (int r = 0; r < 4; ++r) {
        p[sub][r] = exp2f((sv[sub][r] - mn) * LOG2E);
        pk[r] = __builtin_bit_cast(unsigned short, __float2bfloat16(p[sub][r]));
      }
      // P[q=lr][kv=sub*16+lq*4 .. +3] packed 8B write
      *(ushort4v*)&Pw[lr * 68 + sub * 16 + lq * 4] = pk;
      ps += (p[sub][0] + p[sub][1]) + (p[sub][2] + p[sub][3]);
    }
    ps += __shfl_xor(ps, 16, 64);
    ps += __shfl_xor(ps, 32, 64);

    float al = exp2f((mrow - mn) * LOG2E);
    lrow = lrow * al + ps;
    mrow = mn;

    // B-fragment of P: lane supplies P[kv=lq*8+j][q=lr]
    bf16x8 ap0 = *(const bf16x8*)&Pw[lr * 68 + lq * 8];
    bf16x8 ap1 = *(const bf16x8*)&Pw[lr * 68 + 32 + lq * 8];
#pragma unroll
    for (int dt = 0; dt < 4; ++dt) {
#pragma unroll
      for (int r = 0; r < 4; ++r) Oacc[dt][r] *= al;
      Oacc[dt] = __builtin_amdgcn_mfma_f32_16x16x32_bf16(vv[dt][0], ap0, Oacc[dt], 0, 0, 0);
      Oacc[dt] = __builtin_amdgcn_mfma_f32_16x16x32_bf16(vv[dt][1], ap1, Oacc[dt], 0, 0, 0);
    }

    if (ch < tile) {
#pragma unroll
      for (int sub = 0; sub < 4; ++sub) {
        kc[sub][0] = kn[sub][0];
        kc[sub][1] = kn[sub][1];
      }
    }
  }

  // O^T[d=dt*16+lq*4+r][q=lr]; store packed 4 consecutive d per dt
  int b = bh >> 4, h = bh & (NUM_H - 1);
  int q = qw0 + lr;
  size_t base = (((size_t)b * SEQ + q) * NUM_H + h) * 64;
  float rinv = 1.0f / lrow;
#pragma unroll
  for (int dt = 0; dt < 4; ++dt) {
    ushort4v ok;
#pragma unroll
    for (int r = 0; r < 4; ++r)
      ok[r] = __builtin_bit_cast(unsigned short, __float2bfloat16(Oacc[dt][r] * rinv));
    *(ushort4v*)&O[base + dt * 16 + lq * 4] = ok;
  }
}

extern "C" void kernel_launch(void* const* d_in, const int* in_sizes, int n_in,
                              void* d_out, int out_size, void* d_ws, size_t ws_size,
                              hipStream_t stream) {
  const float* x      = (const float*)d_in[0];
  const float* w_qkv  = (const float*)d_in[1];
  const float* b_qkv  = (const float*)d_in[2];
  const float* w_o    = (const float*)d_in[3];
  const float* b_o    = (const float*)d_in[4];
  float* out = (float*)d_out;

  bf16_t* ws    = (bf16_t*)d_ws;
  bf16_t* xb    = ws;                       // [4096,1024]   8MB
  bf16_t* wqkvT = xb + 4 * 1024 * 1024;     // [3072,1024]   6MB
  bf16_t* woT   = wqkvT + 3072 * 1024;      // [1024,1024]   2MB
  bf16_t* Qb    = woT + 1024 * 1024;        // [32,2048,64]  8MB
  bf16_t* Kb    = Qb + 4 * 1024 * 1024;     // [32,2048,64]  8MB
  bf16_t* Vt    = Kb + 4 * 1024 * 1024;     // [32,64,2048]  8MB
  bf16_t* attn  = Vt + 4 * 1024 * 1024;     // [4096,1024]   8MB  (48MB total)

  cast_f32_bf16_kernel<<<4096, 256, 0, stream>>>(x, xb);
  transpose_cast_kernel<<<dim3(96, 32), 256, 0, stream>>>(w_qkv, wqkvT, 1024, 3072);
  transpose_cast_kernel<<<dim3(32, 32), 256, 0, stream>>>(w_o, woT, 1024, 1024);
  gemm_bf16_kernel<0><<<dim3(32, 24), 256, 0, stream>>>(xb, wqkvT, b_qkv, Qb, Kb, Vt, nullptr, 3072, 1024);
  rope_kernel<<<8192, 256, 0, stream>>>(Qb, Kb);
  flash_attn_kernel<<<1024, 256, 0, stream>>>(Qb, Kb, Vt, attn);
  gemm_bf16_kernel<1><<<dim3(32, 8), 256, 0, stream>>>(attn, woT, b_o, nullptr, nullptr, nullptr, out, 1024, 1024);
}